// Round 7
// baseline (211.812 us; speedup 1.0000x reference)
//
#include <hip/hip_runtime.h>
#include <hip/hip_bf16.h>

#define NCH 64
#define SPAN 64            // dst nodes per bucket (dl fits in 6 bits)
#define BIN_BLOCKS 128
#define BIN_THREADS 1024
#define HIST_BLOCKS 256
#define SORT_CAP 3072      // LDS staging capacity per bucket in bucket_sort

using bf16x8 = __attribute__((ext_vector_type(8))) short;   // 8 bf16 = 4 VGPRs
using f32x4 = __attribute__((ext_vector_type(4))) float;

// ---------------------------------------------------------------------------
// Bucket histogram + dtype detection.
// Every block self-detects the index dtype from an 8KB probe (L2-hot).
// Block 0 additionally float-detects and publishes flags for later kernels.
//   flags[0]=1 -> float tensors fp32 (else bf16); flags[1]=1 -> idx int64.
// gcnt must be zeroed beforehand (hipMemsetAsync).
// ---------------------------------------------------------------------------
__global__ void bucket_hist_kernel(const void* __restrict__ dstp,
                                   const unsigned short* __restrict__ gp, int n16,
                                   const unsigned* __restrict__ ip, int niw,
                                   unsigned* __restrict__ flags,
                                   unsigned* __restrict__ gcnt,
                                   int n_edges, int nb) {
    extern __shared__ unsigned lcnt[];                 // [nb] counters + [1] odd
    unsigned* sodd = &lcnt[nb];
    for (int i = threadIdx.x; i < nb; i += blockDim.x) lcnt[i] = 0u;
    if (threadIdx.x == 0) *sodd = 0u;
    __syncthreads();
    // idx dtype: int64 ids (<2^31) -> all odd 32b words zero; int32 -> not.
    unsigned lo = 0u;
    for (int i = threadIdx.x; i < niw; i += blockDim.x)
        if ((i & 1) && ip[i] != 0u) lo++;
    atomicAdd(sodd, lo);
    __syncthreads();
    const unsigned i64 = (*sodd < 50u) ? 1u : 0u;
    if (blockIdx.x == 0 && threadIdx.x == 0) flags[1] = i64;
    if (blockIdx.x == 0) {
        // fp32 viewed as shorts: ~12.5% have "bf16 exponent">=0xC0 (|x|>=2^65).
        unsigned le = 0u;
        for (int i = threadIdx.x; i < n16; i += blockDim.x) {
            unsigned ex = (unsigned)((gp[i] >> 7) & 0xFFu);
            if (ex >= 0xC0u) le++;
        }
        // reuse sodd slot after barrier
        __syncthreads();
        if (threadIdx.x == 0) *sodd = 0u;
        __syncthreads();
        atomicAdd(sodd, le);
        __syncthreads();
        if (threadIdx.x == 0) flags[0] = (*sodd > 50u) ? 1u : 0u;
    }
    const int stride = gridDim.x * blockDim.x;
    for (int e = blockIdx.x * blockDim.x + threadIdx.x; e < n_edges; e += stride) {
        int d = i64 ? (int)((const long long*)dstp)[e] : ((const int*)dstp)[e];
        atomicAdd(&lcnt[d >> 6], 1u);
    }
    __syncthreads();
    for (int i = threadIdx.x; i < nb; i += blockDim.x)
        if (lcnt[i]) atomicAdd(&gcnt[i], lcnt[i]);
}

// ---------------------------------------------------------------------------
// Exclusive scan over nb bucket counts -> boffs (stable) + cursor.
// ---------------------------------------------------------------------------
__global__ void bucket_scan_kernel(const unsigned* __restrict__ gcnt,
                                   unsigned* __restrict__ boffs,
                                   unsigned* __restrict__ cursor, int nb) {
    __shared__ unsigned s[1024];
    const int t = threadIdx.x;
    const int L = (nb + 1023) / 1024;
    unsigned local = 0u;
    for (int i = 0; i < L; ++i) {
        int idx = t * L + i;
        if (idx < nb) local += gcnt[idx];
    }
    s[t] = local;
    __syncthreads();
    for (int off = 1; off < 1024; off <<= 1) {
        unsigned v = (t >= off) ? s[t - off] : 0u;
        __syncthreads();
        s[t] += v;
        __syncthreads();
    }
    unsigned run = s[t] - local;
    for (int i = 0; i < L; ++i) {
        int idx = t * L + i;
        if (idx < nb) { boffs[idx] = run; cursor[idx] = run; run += gcnt[idx]; }
    }
}

// ---------------------------------------------------------------------------
// Binning: scatter packed (dl<<26 | src) into bucket-grouped order.
// LDS staging (depth/bucket) -> global stores flush as contiguous runs.
// ---------------------------------------------------------------------------
__global__ __launch_bounds__(BIN_THREADS)
void binning_kernel(const void* __restrict__ srcp, const void* __restrict__ dstp,
                    unsigned* __restrict__ cursor, unsigned* __restrict__ binned,
                    const unsigned* __restrict__ flags, int n_edges, int nb, int depth) {
    extern __shared__ unsigned lds[];        // [nb] lcnt, then [nb*depth] stage
    unsigned* lcnt = lds;
    unsigned* stage = lds + nb;
    for (int i = threadIdx.x; i < nb; i += blockDim.x) lcnt[i] = 0u;
    __syncthreads();
    const unsigned i64 = flags[1];
    const int chunk = (n_edges + gridDim.x - 1) / gridDim.x;
    const int e0 = blockIdx.x * chunk;
    const int e1 = min(e0 + chunk, n_edges);
    for (int e = e0 + threadIdx.x; e < e1; e += blockDim.x) {
        int s, d;
        if (i64) {
            s = (int)((const long long*)srcp)[e];
            d = (int)((const long long*)dstp)[e];
        } else {
            s = ((const int*)srcp)[e];
            d = ((const int*)dstp)[e];
        }
        const int b = d >> 6;
        const unsigned pk = ((unsigned)(d & 63) << 26) | (unsigned)s;
        unsigned pos = atomicAdd(&lcnt[b], 1u);
        if ((int)pos < depth) {
            stage[b * depth + (int)pos] = pk;
        } else {
            unsigned g = atomicAdd(&cursor[b], 1u);
            binned[g] = pk;
        }
    }
    __syncthreads();
    for (int b = threadIdx.x; b < nb; b += blockDim.x) {
        int k = min((int)lcnt[b], depth);
        if (k > 0) {
            unsigned base = atomicAdd(&cursor[b], (unsigned)k);
            for (int i = 0; i < k; ++i) binned[base + i] = stage[b * depth + i];
        }
    }
}

// ---------------------------------------------------------------------------
// Bucket sort: block = bucket. Count 64 per-node degrees, scan, scatter src
// ids into exact per-node runs inside the contiguous bucket region. Emits
// global CSR offs (offs[n_nodes] = n_edges).
// ---------------------------------------------------------------------------
__global__ __launch_bounds__(256)
void bucket_sort_kernel(const unsigned* __restrict__ binned,
                        const unsigned* __restrict__ boffs,
                        const unsigned* __restrict__ gcnt,
                        unsigned* __restrict__ sorted_src,
                        unsigned* __restrict__ offs,
                        int n_nodes, int n_edges, int nb) {
    __shared__ unsigned dcnt[SPAN];
    __shared__ unsigned doff[SPAN];
    __shared__ unsigned cur[SPAN];
    __shared__ unsigned stage[SORT_CAP];
    const int b = blockIdx.x;
    const int tid = threadIdx.x;
    const int estart = (int)boffs[b];
    const int count = (int)gcnt[b];

    if (tid < SPAN) dcnt[tid] = 0u;
    __syncthreads();

    for (int i = tid; i < count; i += 256) {
        const unsigned pk = binned[estart + i];
        atomicAdd(&dcnt[pk >> 26], 1u);
        if (i < SORT_CAP) stage[i] = pk;
    }
    __syncthreads();

    if (tid == 0) {
        unsigned run = 0u;
        #pragma unroll
        for (int i = 0; i < SPAN; ++i) { doff[i] = run; cur[i] = run; run += dcnt[i]; }
    }
    __syncthreads();

    if (tid < SPAN) {
        const int n = b * SPAN + tid;
        if (n < n_nodes) offs[n] = (unsigned)estart + doff[tid];
    }
    if (b == nb - 1 && tid == 0) offs[n_nodes] = (unsigned)n_edges;

    const int lim = (count < SORT_CAP) ? count : SORT_CAP;
    for (int i = tid; i < lim; i += 256) {
        const unsigned pk = stage[i];
        const unsigned pos = atomicAdd(&cur[pk >> 26], 1u);
        sorted_src[estart + pos] = pk & 0x03FFFFFFu;
    }
    for (int i = SORT_CAP + tid; i < count; i += 256) {   // overflow path
        const unsigned pk = binned[estart + i];
        const unsigned pos = atomicAdd(&cur[pk >> 26], 1u);
        sorted_src[estart + pos] = pk & 0x03FFFFFFu;
    }
}

// ---------------------------------------------------------------------------
// Fused GEMM: rows 0..N-1 -> P = G @ W^T ; rows N..2N-1 -> Q' = RSC @ W^T - b.
// bf16 path: MFMA 16x16x32. Wave = 16-row group; W held as 8 persistent
// B-fragments (B[k][n], n=lane&15, k=(lane>>4)*8+j); A[m=lane&15][k=quad*8+j];
// C/D: col=lane&15, row=quad*4+reg. No LDS, no barriers, streaming.
// fp32 path: old VALU fallback.
// ---------------------------------------------------------------------------
__global__ __launch_bounds__(256)
void gemm2_kernel(const void* __restrict__ Gp, const void* __restrict__ Rp,
                  const void* __restrict__ Wp, const void* __restrict__ bp,
                  void* __restrict__ PQ,
                  const unsigned* __restrict__ flags, int n_nodes) {
    const unsigned f32 = flags[0];
    const int lane = threadIdx.x & 63;
    const int n_rows = 2 * n_nodes;

    if (!f32) {
        // ---------------- MFMA bf16 path ----------------
        const unsigned short* Gh = (const unsigned short*)Gp;
        const unsigned short* Rh = (const unsigned short*)Rp;
        const unsigned short* Wh = (const unsigned short*)Wp;
        const __hip_bfloat16* bh = (const __hip_bfloat16*)bp;
        __hip_bfloat16* out = (__hip_bfloat16*)PQ;
        const int q = lane >> 4;            // quad 0..3
        const int mr = lane & 15;
        const int gwave = (blockIdx.x * blockDim.x + threadIdx.x) >> 6;
        const int nwaves = (gridDim.x * blockDim.x) >> 6;
        const int ngrp = (n_rows + 15) / 16;

        bf16x8 Bf[4][2];
        float bv[4];
        #pragma unroll
        for (int t = 0; t < 4; ++t) {
            const int c = t * 16 + mr;      // output channel (W row)
            Bf[t][0] = *(const bf16x8*)(const void*)(Wh + (size_t)c * NCH + q * 8);
            Bf[t][1] = *(const bf16x8*)(const void*)(Wh + (size_t)c * NCH + 32 + q * 8);
            bv[t] = __bfloat162float(bh[c]);
        }

        for (int grp = gwave; grp < ngrp; grp += nwaves) {
            const int m0 = grp * 16;
            int arow = m0 + mr;
            if (arow >= n_rows) arow = n_rows - 1;     // clamp: OOB D rows unstored
            const unsigned short* ap = (arow < n_nodes)
                ? Gh + (size_t)arow * NCH
                : Rh + (size_t)(arow - n_nodes) * NCH;
            const bf16x8 A0 = *(const bf16x8*)(const void*)(ap + q * 8);
            const bf16x8 A1 = *(const bf16x8*)(const void*)(ap + 32 + q * 8);
            f32x4 acc0 = {0.f, 0.f, 0.f, 0.f}, acc1 = acc0, acc2 = acc0, acc3 = acc0;
            acc0 = __builtin_amdgcn_mfma_f32_16x16x32_bf16(A0, Bf[0][0], acc0, 0, 0, 0);
            acc1 = __builtin_amdgcn_mfma_f32_16x16x32_bf16(A0, Bf[1][0], acc1, 0, 0, 0);
            acc2 = __builtin_amdgcn_mfma_f32_16x16x32_bf16(A0, Bf[2][0], acc2, 0, 0, 0);
            acc3 = __builtin_amdgcn_mfma_f32_16x16x32_bf16(A0, Bf[3][0], acc3, 0, 0, 0);
            acc0 = __builtin_amdgcn_mfma_f32_16x16x32_bf16(A1, Bf[0][1], acc0, 0, 0, 0);
            acc1 = __builtin_amdgcn_mfma_f32_16x16x32_bf16(A1, Bf[1][1], acc1, 0, 0, 0);
            acc2 = __builtin_amdgcn_mfma_f32_16x16x32_bf16(A1, Bf[2][1], acc2, 0, 0, 0);
            acc3 = __builtin_amdgcn_mfma_f32_16x16x32_bf16(A1, Bf[3][1], acc3, 0, 0, 0);
            #pragma unroll
            for (int r = 0; r < 4; ++r) {
                const int row = m0 + q * 4 + r;
                if (row < n_rows) {
                    const bool isQ = (row >= n_nodes);
                    const size_t rb = (size_t)row * NCH + mr;
                    out[rb +  0] = __float2bfloat16(acc0[r] - (isQ ? bv[0] : 0.f));
                    out[rb + 16] = __float2bfloat16(acc1[r] - (isQ ? bv[1] : 0.f));
                    out[rb + 32] = __float2bfloat16(acc2[r] - (isQ ? bv[2] : 0.f));
                    out[rb + 48] = __float2bfloat16(acc3[r] - (isQ ? bv[3] : 0.f));
                }
            }
        }
        return;
    }

    // ---------------- fp32 VALU fallback ----------------
    const int waveInBlk = threadIdx.x >> 6;
    const int wavesPerBlk = blockDim.x >> 6;
    const int gwave = blockIdx.x * wavesPerBlk + waveInBlk;
    const int nwaves = gridDim.x * wavesPerBlk;
    const int ngroups = (n_rows + 3) / 4;

    __shared__ float ldsb[4 * 4 * NCH];
    float* slot = &ldsb[waveInBlk * 4 * NCH];

    float w[NCH];
    const float* Wf = (const float*)Wp;
    #pragma unroll
    for (int k = 0; k < NCH; ++k) w[k] = Wf[lane * NCH + k];
    const float bias = ((const float*)bp)[lane];

    const int niter = (ngroups + nwaves - 1) / nwaves;
    for (int it = 0; it < niter; ++it) {
        const int grp = gwave + it * nwaves;
        const bool gvalid = (grp < ngroups);
        const int m0 = grp * 4;
        if (gvalid) {
            const int myrow = m0 + (lane >> 4);
            const int col = (lane & 15) * 4;
            float x0 = 0.f, x1 = 0.f, x2 = 0.f, x3 = 0.f;
            if (myrow < n_rows) {
                const bool isQ = (myrow >= n_nodes);
                const int r = isQ ? (myrow - n_nodes) : myrow;
                const float* inp = (const float*)(isQ ? Rp : Gp);
                float4 v = *(const float4*)(inp + (size_t)r * NCH + col);
                x0 = v.x; x1 = v.y; x2 = v.z; x3 = v.w;
            }
            const int sb = (lane >> 4) * NCH + col;
            slot[sb + 0] = x0; slot[sb + 1] = x1; slot[sb + 2] = x2; slot[sb + 3] = x3;
        }
        __syncthreads();
        if (gvalid) {
            #pragma unroll
            for (int rr = 0; rr < 4; ++rr) {
                const int m = m0 + rr;
                if (m < n_rows) {
                    float a0 = 0.f, a1 = 0.f, a2 = 0.f, a3 = 0.f;
                    const float4* r4 = (const float4*)(slot + rr * NCH);
                    #pragma unroll
                    for (int qq = 0; qq < 16; ++qq) {
                        float4 rv = r4[qq];
                        a0 = fmaf(rv.x, w[4 * qq + 0], a0);
                        a1 = fmaf(rv.y, w[4 * qq + 1], a1);
                        a2 = fmaf(rv.z, w[4 * qq + 2], a2);
                        a3 = fmaf(rv.w, w[4 * qq + 3], a3);
                    }
                    float acc = (a0 + a1) + (a2 + a3);
                    if (m >= n_nodes) acc -= bias;
                    ((float*)PQ)[(size_t)m * NCH + lane] = acc;
                }
            }
        }
        __syncthreads();
    }
}

// ---------------------------------------------------------------------------
// One wave per node (grid-stride), lane = channel. Register-lean, no LDS ->
// full occupancy for gather-latency hiding (round-5 lesson). Unrolled x8.
// ---------------------------------------------------------------------------
__global__ void node_kernel(const void* __restrict__ PQ,
                            const unsigned* __restrict__ sorted_src,
                            const unsigned* __restrict__ offs,
                            const unsigned* __restrict__ flags,
                            void* __restrict__ outp, int n_nodes) {
    const unsigned f32 = flags[0];
    const int lane = threadIdx.x & 63;
    const int gwave = (blockIdx.x * blockDim.x + threadIdx.x) >> 6;
    const int nwaves = (gridDim.x * blockDim.x) >> 6;
    const float* Pf = (const float*)PQ;
    const unsigned short* Ph = (const unsigned short*)PQ;

    for (int n = gwave; n < n_nodes; n += nwaves) {
        float q;
        if (f32) q = Pf[(size_t)(n_nodes + n) * NCH + lane];
        else {
            unsigned short h = Ph[(size_t)(n_nodes + n) * NCH + lane];
            q = __bfloat162float(*(__hip_bfloat16*)&h);
        }
        const int start = (int)offs[n];
        const int end = (int)offs[n + 1];
        float vmax = 0.0f, vsum = 0.0f;
        int j = start;
        for (; j + 8 <= end; j += 8) {
            int s[8];
            #pragma unroll
            for (int u = 0; u < 8; ++u) s[u] = (int)sorted_src[j + u];
            float p[8];
            if (f32) {
                #pragma unroll
                for (int u = 0; u < 8; ++u) p[u] = Pf[(size_t)s[u] * NCH + lane];
            } else {
                unsigned short h[8];
                #pragma unroll
                for (int u = 0; u < 8; ++u) h[u] = Ph[(size_t)s[u] * NCH + lane];
                #pragma unroll
                for (int u = 0; u < 8; ++u) p[u] = __bfloat162float(*(__hip_bfloat16*)&h[u]);
            }
            #pragma unroll
            for (int u = 0; u < 8; ++u) {
                const float v = fmaxf(p[u] - q, 0.0f);
                vmax = fmaxf(vmax, v);
                vsum += v;
            }
        }
        for (; j < end; ++j) {
            const int s = (int)sorted_src[j];
            float p;
            if (f32) p = Pf[(size_t)s * NCH + lane];
            else {
                unsigned short h = Ph[(size_t)s * NCH + lane];
                p = __bfloat162float(*(__hip_bfloat16*)&h);
            }
            const float v = fmaxf(p - q, 0.0f);
            vmax = fmaxf(vmax, v);
            vsum += v;
        }
        const int deg = end - start;
        const float avg = vsum / (float)(deg > 0 ? deg : 1);
        if (f32) {
            float* out = (float*)outp;
            out[(size_t)n * 2 * NCH + lane] = vmax;
            out[(size_t)n * 2 * NCH + NCH + lane] = avg;
        } else {
            __hip_bfloat16* out = (__hip_bfloat16*)outp;
            out[(size_t)n * 2 * NCH + lane] = __float2bfloat16(vmax);
            out[(size_t)n * 2 * NCH + NCH + lane] = __float2bfloat16(avg);
        }
    }
}

extern "C" void kernel_launch(void* const* d_in, const int* in_sizes, int n_in,
                              void* d_out, int out_size, void* d_ws, size_t ws_size,
                              hipStream_t stream) {
    const void* G = d_in[0];
    const void* RSC = d_in[1];
    const void* src = d_in[2];
    const void* dst = d_in[3];
    const void* W = d_in[4];
    const void* b = d_in[5];

    const int n_nodes = in_sizes[0] / NCH;
    const int n_edges = in_sizes[2];
    const int nb = (n_nodes + SPAN - 1) / SPAN;

    // ws layout (bytes): [flags 256][binned 4E][sorted 4E][offs 4(N+1)]
    //                    [boffs 4nb][cursor 4nb][gcnt 4nb][PQ dtype*64*2N]
    char* ws = (char*)d_ws;
    unsigned* flags = (unsigned*)ws;
    size_t off = 256;
    unsigned* binned = (unsigned*)(ws + off);
    off += (((size_t)n_edges * 4 + 255) / 256) * 256;
    unsigned* sorted_src = (unsigned*)(ws + off);
    off += (((size_t)n_edges * 4 + 255) / 256) * 256;
    unsigned* offs = (unsigned*)(ws + off);
    off += (((size_t)(n_nodes + 1) * 4 + 255) / 256) * 256;
    unsigned* boffs = (unsigned*)(ws + off);
    off += (((size_t)nb * 4 + 255) / 256) * 256;
    unsigned* cursor = (unsigned*)(ws + off);
    off += (((size_t)nb * 4 + 255) / 256) * 256;
    unsigned* gcnt = (unsigned*)(ws + off);
    off += (((size_t)nb * 4 + 255) / 256) * 256;
    void* PQ = (void*)(ws + off);                   // fp32 or bf16 per flags[0]

    const int n_g_probe = (in_sizes[0] < 8192) ? in_sizes[0] : 8192;
    const int n_idx_probe = (n_edges < 8192) ? n_edges : 8192;

    hipMemsetAsync(gcnt, 0, (size_t)nb * 4, stream);

    bucket_hist_kernel<<<HIST_BLOCKS, 256, (size_t)(nb + 1) * 4, stream>>>(
        dst, (const unsigned short*)G, n_g_probe, (const unsigned*)src, n_idx_probe,
        flags, gcnt, n_edges, nb);

    bucket_scan_kernel<<<1, 1024, 0, stream>>>(gcnt, boffs, cursor, nb);

    int depth = 16384 / nb - 1;                     // keep dyn LDS <= 64 KB
    if (depth > 19) depth = 19;
    if (depth < 4) depth = 4;
    const size_t bin_lds = (size_t)nb * (depth + 1) * 4;
    binning_kernel<<<BIN_BLOCKS, BIN_THREADS, bin_lds, stream>>>(
        src, dst, cursor, binned, flags, n_edges, nb, depth);

    bucket_sort_kernel<<<nb, 256, 0, stream>>>(binned, boffs, gcnt, sorted_src,
                                               offs, n_nodes, n_edges, nb);

    const int ngrp = (2 * n_nodes + 15) / 16;
    gemm2_kernel<<<(ngrp + 3) / 4, 256, 0, stream>>>(G, RSC, W, b, PQ, flags, n_nodes);

    node_kernel<<<2048, 256, 0, stream>>>(PQ, sorted_src, offs, flags, d_out, n_nodes);
}

// Round 8
// 200.338 us; speedup vs baseline: 1.0573x; 1.0573x over previous
//
#include <hip/hip_runtime.h>
#include <hip/hip_bf16.h>

#define NCH 64
#define SPAN 64            // dst nodes per bucket (dl fits in 6 bits)
#define BIN_BLOCKS 128
#define BIN_THREADS 1024
#define HIST_BLOCKS 256
#define SORT_CAP 3072      // LDS staging capacity per bucket in bucket_sort

using bf16x8 = __attribute__((ext_vector_type(8))) short;   // 8 bf16 = 4 VGPRs
using f32x4 = __attribute__((ext_vector_type(4))) float;

// ---------------------------------------------------------------------------
// Bucket histogram + dtype detection.
// Every block self-detects the index dtype from an 8KB probe (L2-hot).
// Block 0 additionally float-detects and publishes flags for later kernels.
//   flags[0]=1 -> float tensors fp32 (else bf16); flags[1]=1 -> idx int64.
// gcnt must be zeroed beforehand (hipMemsetAsync).
// ---------------------------------------------------------------------------
__global__ void bucket_hist_kernel(const void* __restrict__ dstp,
                                   const unsigned short* __restrict__ gp, int n16,
                                   const unsigned* __restrict__ ip, int niw,
                                   unsigned* __restrict__ flags,
                                   unsigned* __restrict__ gcnt,
                                   int n_edges, int nb) {
    extern __shared__ unsigned lcnt[];                 // [nb] counters + [1] odd
    unsigned* sodd = &lcnt[nb];
    for (int i = threadIdx.x; i < nb; i += blockDim.x) lcnt[i] = 0u;
    if (threadIdx.x == 0) *sodd = 0u;
    __syncthreads();
    // idx dtype: int64 ids (<2^31) -> all odd 32b words zero; int32 -> not.
    unsigned lo = 0u;
    for (int i = threadIdx.x; i < niw; i += blockDim.x)
        if ((i & 1) && ip[i] != 0u) lo++;
    atomicAdd(sodd, lo);
    __syncthreads();
    const unsigned i64 = (*sodd < 50u) ? 1u : 0u;
    if (blockIdx.x == 0 && threadIdx.x == 0) flags[1] = i64;
    if (blockIdx.x == 0) {
        // fp32 viewed as shorts: ~12.5% have "bf16 exponent">=0xC0 (|x|>=2^65).
        unsigned le = 0u;
        for (int i = threadIdx.x; i < n16; i += blockDim.x) {
            unsigned ex = (unsigned)((gp[i] >> 7) & 0xFFu);
            if (ex >= 0xC0u) le++;
        }
        __syncthreads();
        if (threadIdx.x == 0) *sodd = 0u;
        __syncthreads();
        atomicAdd(sodd, le);
        __syncthreads();
        if (threadIdx.x == 0) flags[0] = (*sodd > 50u) ? 1u : 0u;
    }
    const int stride = gridDim.x * blockDim.x;
    for (int e = blockIdx.x * blockDim.x + threadIdx.x; e < n_edges; e += stride) {
        int d = i64 ? (int)((const long long*)dstp)[e] : ((const int*)dstp)[e];
        atomicAdd(&lcnt[d >> 6], 1u);
    }
    __syncthreads();
    for (int i = threadIdx.x; i < nb; i += blockDim.x)
        if (lcnt[i]) atomicAdd(&gcnt[i], lcnt[i]);
}

// ---------------------------------------------------------------------------
// Exclusive scan over nb bucket counts -> boffs (stable) + cursor.
// ---------------------------------------------------------------------------
__global__ void bucket_scan_kernel(const unsigned* __restrict__ gcnt,
                                   unsigned* __restrict__ boffs,
                                   unsigned* __restrict__ cursor, int nb) {
    __shared__ unsigned s[1024];
    const int t = threadIdx.x;
    const int L = (nb + 1023) / 1024;
    unsigned local = 0u;
    for (int i = 0; i < L; ++i) {
        int idx = t * L + i;
        if (idx < nb) local += gcnt[idx];
    }
    s[t] = local;
    __syncthreads();
    for (int off = 1; off < 1024; off <<= 1) {
        unsigned v = (t >= off) ? s[t - off] : 0u;
        __syncthreads();
        s[t] += v;
        __syncthreads();
    }
    unsigned run = s[t] - local;
    for (int i = 0; i < L; ++i) {
        int idx = t * L + i;
        if (idx < nb) { boffs[idx] = run; cursor[idx] = run; run += gcnt[idx]; }
    }
}

// ---------------------------------------------------------------------------
// Binning: scatter packed (dl<<26 | src) into bucket-grouped order.
// LDS staging (depth/bucket) -> global stores flush as contiguous runs.
// ---------------------------------------------------------------------------
__global__ __launch_bounds__(BIN_THREADS)
void binning_kernel(const void* __restrict__ srcp, const void* __restrict__ dstp,
                    unsigned* __restrict__ cursor, unsigned* __restrict__ binned,
                    const unsigned* __restrict__ flags, int n_edges, int nb, int depth) {
    extern __shared__ unsigned lds[];        // [nb] lcnt, then [nb*depth] stage
    unsigned* lcnt = lds;
    unsigned* stage = lds + nb;
    for (int i = threadIdx.x; i < nb; i += blockDim.x) lcnt[i] = 0u;
    __syncthreads();
    const unsigned i64 = flags[1];
    const int chunk = (n_edges + gridDim.x - 1) / gridDim.x;
    const int e0 = blockIdx.x * chunk;
    const int e1 = min(e0 + chunk, n_edges);
    for (int e = e0 + threadIdx.x; e < e1; e += blockDim.x) {
        int s, d;
        if (i64) {
            s = (int)((const long long*)srcp)[e];
            d = (int)((const long long*)dstp)[e];
        } else {
            s = ((const int*)srcp)[e];
            d = ((const int*)dstp)[e];
        }
        const int b = d >> 6;
        const unsigned pk = ((unsigned)(d & 63) << 26) | (unsigned)s;
        unsigned pos = atomicAdd(&lcnt[b], 1u);
        if ((int)pos < depth) {
            stage[b * depth + (int)pos] = pk;
        } else {
            unsigned g = atomicAdd(&cursor[b], 1u);
            binned[g] = pk;
        }
    }
    __syncthreads();
    for (int b = threadIdx.x; b < nb; b += blockDim.x) {
        int k = min((int)lcnt[b], depth);
        if (k > 0) {
            unsigned base = atomicAdd(&cursor[b], (unsigned)k);
            for (int i = 0; i < k; ++i) binned[base + i] = stage[b * depth + i];
        }
    }
}

// ---------------------------------------------------------------------------
// Bucket sort: block = bucket. Count 64 per-node degrees, scan, scatter src
// ids into exact per-node runs inside the contiguous bucket region. Emits
// global CSR offs (offs[n_nodes] = n_edges).
// ---------------------------------------------------------------------------
__global__ __launch_bounds__(256)
void bucket_sort_kernel(const unsigned* __restrict__ binned,
                        const unsigned* __restrict__ boffs,
                        const unsigned* __restrict__ gcnt,
                        unsigned* __restrict__ sorted_src,
                        unsigned* __restrict__ offs,
                        int n_nodes, int n_edges, int nb) {
    __shared__ unsigned dcnt[SPAN];
    __shared__ unsigned doff[SPAN];
    __shared__ unsigned cur[SPAN];
    __shared__ unsigned stage[SORT_CAP];
    const int b = blockIdx.x;
    const int tid = threadIdx.x;
    const int estart = (int)boffs[b];
    const int count = (int)gcnt[b];

    if (tid < SPAN) dcnt[tid] = 0u;
    __syncthreads();

    for (int i = tid; i < count; i += 256) {
        const unsigned pk = binned[estart + i];
        atomicAdd(&dcnt[pk >> 26], 1u);
        if (i < SORT_CAP) stage[i] = pk;
    }
    __syncthreads();

    if (tid == 0) {
        unsigned run = 0u;
        #pragma unroll
        for (int i = 0; i < SPAN; ++i) { doff[i] = run; cur[i] = run; run += dcnt[i]; }
    }
    __syncthreads();

    if (tid < SPAN) {
        const int n = b * SPAN + tid;
        if (n < n_nodes) offs[n] = (unsigned)estart + doff[tid];
    }
    if (b == nb - 1 && tid == 0) offs[n_nodes] = (unsigned)n_edges;

    const int lim = (count < SORT_CAP) ? count : SORT_CAP;
    for (int i = tid; i < lim; i += 256) {
        const unsigned pk = stage[i];
        const unsigned pos = atomicAdd(&cur[pk >> 26], 1u);
        sorted_src[estart + pos] = pk & 0x03FFFFFFu;
    }
    for (int i = SORT_CAP + tid; i < count; i += 256) {   // overflow path
        const unsigned pk = binned[estart + i];
        const unsigned pos = atomicAdd(&cur[pk >> 26], 1u);
        sorted_src[estart + pos] = pk & 0x03FFFFFFu;
    }
}

// ---------------------------------------------------------------------------
// Fused GEMM: rows 0..N-1 -> P = G @ W^T ; rows N..2N-1 -> Q' = RSC @ W^T - b.
// bf16 path: MFMA 16x16x32, wave = 16-row group, W held as 8 persistent
// B-fragments. FIXED grid (512 blocks): each wave loops ~3 groups so the
// per-wave W preamble amortizes, and next group's A-fragments are prefetched
// before the current group's MFMAs (2 groups of A in flight per wave).
// fp32 path: VALU fallback.
// ---------------------------------------------------------------------------
__global__ __launch_bounds__(256)
void gemm2_kernel(const void* __restrict__ Gp, const void* __restrict__ Rp,
                  const void* __restrict__ Wp, const void* __restrict__ bp,
                  void* __restrict__ PQ,
                  const unsigned* __restrict__ flags, int n_nodes) {
    const unsigned f32 = flags[0];
    const int lane = threadIdx.x & 63;
    const int n_rows = 2 * n_nodes;

    if (!f32) {
        // ---------------- MFMA bf16 path ----------------
        const unsigned short* Gh = (const unsigned short*)Gp;
        const unsigned short* Rh = (const unsigned short*)Rp;
        const unsigned short* Wh = (const unsigned short*)Wp;
        const __hip_bfloat16* bh = (const __hip_bfloat16*)bp;
        __hip_bfloat16* out = (__hip_bfloat16*)PQ;
        const int q = lane >> 4;            // quad 0..3
        const int mr = lane & 15;
        const int gwave = (blockIdx.x * blockDim.x + threadIdx.x) >> 6;
        const int nwaves = (gridDim.x * blockDim.x) >> 6;
        const int ngrp = (n_rows + 15) / 16;

        bf16x8 Bf[4][2];
        float bv[4];
        #pragma unroll
        for (int t = 0; t < 4; ++t) {
            const int c = t * 16 + mr;      // output channel (W row)
            Bf[t][0] = *(const bf16x8*)(const void*)(Wh + (size_t)c * NCH + q * 8);
            Bf[t][1] = *(const bf16x8*)(const void*)(Wh + (size_t)c * NCH + 32 + q * 8);
            bv[t] = __bfloat162float(bh[c]);
        }

        auto rowptr = [&](int grp) -> const unsigned short* {
            int arow = grp * 16 + mr;
            if (arow >= n_rows) arow = n_rows - 1;   // clamp: OOB D rows unstored
            return (arow < n_nodes) ? Gh + (size_t)arow * NCH
                                    : Rh + (size_t)(arow - n_nodes) * NCH;
        };

        bf16x8 A0, A1;
        if (gwave < ngrp) {
            const unsigned short* ap = rowptr(gwave);
            A0 = *(const bf16x8*)(const void*)(ap + q * 8);
            A1 = *(const bf16x8*)(const void*)(ap + 32 + q * 8);
        }
        for (int grp = gwave; grp < ngrp; grp += nwaves) {
            // prefetch next group's A before consuming this group's
            bf16x8 nA0, nA1;
            const int nxt = grp + nwaves;
            if (nxt < ngrp) {
                const unsigned short* ap = rowptr(nxt);
                nA0 = *(const bf16x8*)(const void*)(ap + q * 8);
                nA1 = *(const bf16x8*)(const void*)(ap + 32 + q * 8);
            }
            f32x4 acc0 = {0.f, 0.f, 0.f, 0.f}, acc1 = acc0, acc2 = acc0, acc3 = acc0;
            acc0 = __builtin_amdgcn_mfma_f32_16x16x32_bf16(A0, Bf[0][0], acc0, 0, 0, 0);
            acc1 = __builtin_amdgcn_mfma_f32_16x16x32_bf16(A0, Bf[1][0], acc1, 0, 0, 0);
            acc2 = __builtin_amdgcn_mfma_f32_16x16x32_bf16(A0, Bf[2][0], acc2, 0, 0, 0);
            acc3 = __builtin_amdgcn_mfma_f32_16x16x32_bf16(A0, Bf[3][0], acc3, 0, 0, 0);
            acc0 = __builtin_amdgcn_mfma_f32_16x16x32_bf16(A1, Bf[0][1], acc0, 0, 0, 0);
            acc1 = __builtin_amdgcn_mfma_f32_16x16x32_bf16(A1, Bf[1][1], acc1, 0, 0, 0);
            acc2 = __builtin_amdgcn_mfma_f32_16x16x32_bf16(A1, Bf[2][1], acc2, 0, 0, 0);
            acc3 = __builtin_amdgcn_mfma_f32_16x16x32_bf16(A1, Bf[3][1], acc3, 0, 0, 0);
            const int m0 = grp * 16;
            #pragma unroll
            for (int r = 0; r < 4; ++r) {
                const int row = m0 + q * 4 + r;
                if (row < n_rows) {
                    const bool isQ = (row >= n_nodes);
                    const size_t rb = (size_t)row * NCH + mr;
                    out[rb +  0] = __float2bfloat16(acc0[r] - (isQ ? bv[0] : 0.f));
                    out[rb + 16] = __float2bfloat16(acc1[r] - (isQ ? bv[1] : 0.f));
                    out[rb + 32] = __float2bfloat16(acc2[r] - (isQ ? bv[2] : 0.f));
                    out[rb + 48] = __float2bfloat16(acc3[r] - (isQ ? bv[3] : 0.f));
                }
            }
            A0 = nA0; A1 = nA1;
        }
        return;
    }

    // ---------------- fp32 VALU fallback ----------------
    const int waveInBlk = threadIdx.x >> 6;
    const int wavesPerBlk = blockDim.x >> 6;
    const int gwave = blockIdx.x * wavesPerBlk + waveInBlk;
    const int nwaves = gridDim.x * wavesPerBlk;
    const int ngroups = (n_rows + 3) / 4;

    __shared__ float ldsb[4 * 4 * NCH];
    float* slot = &ldsb[waveInBlk * 4 * NCH];

    float w[NCH];
    const float* Wf = (const float*)Wp;
    #pragma unroll
    for (int k = 0; k < NCH; ++k) w[k] = Wf[lane * NCH + k];
    const float bias = ((const float*)bp)[lane];

    const int niter = (ngroups + nwaves - 1) / nwaves;
    for (int it = 0; it < niter; ++it) {
        const int grp = gwave + it * nwaves;
        const bool gvalid = (grp < ngroups);
        const int m0 = grp * 4;
        if (gvalid) {
            const int myrow = m0 + (lane >> 4);
            const int col = (lane & 15) * 4;
            float x0 = 0.f, x1 = 0.f, x2 = 0.f, x3 = 0.f;
            if (myrow < n_rows) {
                const bool isQ = (myrow >= n_nodes);
                const int r = isQ ? (myrow - n_nodes) : myrow;
                const float* inp = (const float*)(isQ ? Rp : Gp);
                float4 v = *(const float4*)(inp + (size_t)r * NCH + col);
                x0 = v.x; x1 = v.y; x2 = v.z; x3 = v.w;
            }
            const int sb = (lane >> 4) * NCH + col;
            slot[sb + 0] = x0; slot[sb + 1] = x1; slot[sb + 2] = x2; slot[sb + 3] = x3;
        }
        __syncthreads();
        if (gvalid) {
            #pragma unroll
            for (int rr = 0; rr < 4; ++rr) {
                const int m = m0 + rr;
                if (m < n_rows) {
                    float a0 = 0.f, a1 = 0.f, a2 = 0.f, a3 = 0.f;
                    const float4* r4 = (const float4*)(slot + rr * NCH);
                    #pragma unroll
                    for (int qq = 0; qq < 16; ++qq) {
                        float4 rv = r4[qq];
                        a0 = fmaf(rv.x, w[4 * qq + 0], a0);
                        a1 = fmaf(rv.y, w[4 * qq + 1], a1);
                        a2 = fmaf(rv.z, w[4 * qq + 2], a2);
                        a3 = fmaf(rv.w, w[4 * qq + 3], a3);
                    }
                    float acc = (a0 + a1) + (a2 + a3);
                    if (m >= n_nodes) acc -= bias;
                    ((float*)PQ)[(size_t)m * NCH + lane] = acc;
                }
            }
        }
        __syncthreads();
    }
}

// ---------------------------------------------------------------------------
// One wave per node (grid-stride), lane = channel. Register-lean, no LDS ->
// full occupancy for gather-latency hiding (round-5 lesson). Unrolled x8.
// ---------------------------------------------------------------------------
__global__ void node_kernel(const void* __restrict__ PQ,
                            const unsigned* __restrict__ sorted_src,
                            const unsigned* __restrict__ offs,
                            const unsigned* __restrict__ flags,
                            void* __restrict__ outp, int n_nodes) {
    const unsigned f32 = flags[0];
    const int lane = threadIdx.x & 63;
    const int gwave = (blockIdx.x * blockDim.x + threadIdx.x) >> 6;
    const int nwaves = (gridDim.x * blockDim.x) >> 6;
    const float* Pf = (const float*)PQ;
    const unsigned short* Ph = (const unsigned short*)PQ;

    for (int n = gwave; n < n_nodes; n += nwaves) {
        float q;
        if (f32) q = Pf[(size_t)(n_nodes + n) * NCH + lane];
        else {
            unsigned short h = Ph[(size_t)(n_nodes + n) * NCH + lane];
            q = __bfloat162float(*(__hip_bfloat16*)&h);
        }
        const int start = (int)offs[n];
        const int end = (int)offs[n + 1];
        float vmax = 0.0f, vsum = 0.0f;
        int j = start;
        for (; j + 8 <= end; j += 8) {
            int s[8];
            #pragma unroll
            for (int u = 0; u < 8; ++u) s[u] = (int)sorted_src[j + u];
            float p[8];
            if (f32) {
                #pragma unroll
                for (int u = 0; u < 8; ++u) p[u] = Pf[(size_t)s[u] * NCH + lane];
            } else {
                unsigned short h[8];
                #pragma unroll
                for (int u = 0; u < 8; ++u) h[u] = Ph[(size_t)s[u] * NCH + lane];
                #pragma unroll
                for (int u = 0; u < 8; ++u) p[u] = __bfloat162float(*(__hip_bfloat16*)&h[u]);
            }
            #pragma unroll
            for (int u = 0; u < 8; ++u) {
                const float v = fmaxf(p[u] - q, 0.0f);
                vmax = fmaxf(vmax, v);
                vsum += v;
            }
        }
        for (; j < end; ++j) {
            const int s = (int)sorted_src[j];
            float p;
            if (f32) p = Pf[(size_t)s * NCH + lane];
            else {
                unsigned short h = Ph[(size_t)s * NCH + lane];
                p = __bfloat162float(*(__hip_bfloat16*)&h);
            }
            const float v = fmaxf(p - q, 0.0f);
            vmax = fmaxf(vmax, v);
            vsum += v;
        }
        const int deg = end - start;
        const float avg = vsum / (float)(deg > 0 ? deg : 1);
        if (f32) {
            float* out = (float*)outp;
            out[(size_t)n * 2 * NCH + lane] = vmax;
            out[(size_t)n * 2 * NCH + NCH + lane] = avg;
        } else {
            __hip_bfloat16* out = (__hip_bfloat16*)outp;
            out[(size_t)n * 2 * NCH + lane] = __float2bfloat16(vmax);
            out[(size_t)n * 2 * NCH + NCH + lane] = __float2bfloat16(avg);
        }
    }
}

extern "C" void kernel_launch(void* const* d_in, const int* in_sizes, int n_in,
                              void* d_out, int out_size, void* d_ws, size_t ws_size,
                              hipStream_t stream) {
    const void* G = d_in[0];
    const void* RSC = d_in[1];
    const void* src = d_in[2];
    const void* dst = d_in[3];
    const void* W = d_in[4];
    const void* b = d_in[5];

    const int n_nodes = in_sizes[0] / NCH;
    const int n_edges = in_sizes[2];
    const int nb = (n_nodes + SPAN - 1) / SPAN;

    // ws layout (bytes): [flags 256][binned 4E][sorted 4E][offs 4(N+1)]
    //                    [boffs 4nb][cursor 4nb][gcnt 4nb][PQ dtype*64*2N]
    char* ws = (char*)d_ws;
    unsigned* flags = (unsigned*)ws;
    size_t off = 256;
    unsigned* binned = (unsigned*)(ws + off);
    off += (((size_t)n_edges * 4 + 255) / 256) * 256;
    unsigned* sorted_src = (unsigned*)(ws + off);
    off += (((size_t)n_edges * 4 + 255) / 256) * 256;
    unsigned* offs = (unsigned*)(ws + off);
    off += (((size_t)(n_nodes + 1) * 4 + 255) / 256) * 256;
    unsigned* boffs = (unsigned*)(ws + off);
    off += (((size_t)nb * 4 + 255) / 256) * 256;
    unsigned* cursor = (unsigned*)(ws + off);
    off += (((size_t)nb * 4 + 255) / 256) * 256;
    unsigned* gcnt = (unsigned*)(ws + off);
    off += (((size_t)nb * 4 + 255) / 256) * 256;
    void* PQ = (void*)(ws + off);                   // fp32 or bf16 per flags[0]

    const int n_g_probe = (in_sizes[0] < 8192) ? in_sizes[0] : 8192;
    const int n_idx_probe = (n_edges < 8192) ? n_edges : 8192;

    hipMemsetAsync(gcnt, 0, (size_t)nb * 4, stream);

    bucket_hist_kernel<<<HIST_BLOCKS, 256, (size_t)(nb + 1) * 4, stream>>>(
        dst, (const unsigned short*)G, n_g_probe, (const unsigned*)src, n_idx_probe,
        flags, gcnt, n_edges, nb);

    bucket_scan_kernel<<<1, 1024, 0, stream>>>(gcnt, boffs, cursor, nb);

    int depth = 16384 / nb - 1;                     // keep dyn LDS <= 64 KB
    if (depth > 19) depth = 19;
    if (depth < 4) depth = 4;
    const size_t bin_lds = (size_t)nb * (depth + 1) * 4;
    binning_kernel<<<BIN_BLOCKS, BIN_THREADS, bin_lds, stream>>>(
        src, dst, cursor, binned, flags, n_edges, nb, depth);

    bucket_sort_kernel<<<nb, 256, 0, stream>>>(binned, boffs, gcnt, sorted_src,
                                               offs, n_nodes, n_edges, nb);

    // 512 blocks = 2048 waves: ~3 groups/wave (W preamble amortized) + prefetch
    gemm2_kernel<<<512, 256, 0, stream>>>(G, RSC, W, b, PQ, flags, n_nodes);

    node_kernel<<<2048, 256, 0, stream>>>(PQ, sorted_src, offs, flags, d_out, n_nodes);
}